// Round 8
// baseline (80.539 us; speedup 1.0000x reference)
//
#include <hip/hip_runtime.h>
#include <hip/hip_bf16.h>
#include <math.h>

// SparseFlashAttention: B=2, S=2048, H=16, D=64, fp32 in/out, [S,S] bool mask.
#define SLEN 2048
#define NBATCH 2
#define NH 16
#define DH 64
#define WPR 64      // mask words per row
#define NROUND 32   // 64-key rounds
#define IMGB 8192   // bytes per 64x64 bf16 swizzled image
#define CONVBLK (NBATCH * NH * NROUND)          // 1024 conv blocks
#define PACKBLK (SLEN * WPR / 256)              // 512 pack blocks

typedef __attribute__((ext_vector_type(4))) short short4v;
typedef __attribute__((ext_vector_type(8))) short short8v;
typedef __attribute__((ext_vector_type(4))) float float4v;
typedef __attribute__((ext_vector_type(16))) float float16v;

typedef __attribute__((address_space(1))) void gas_void;
typedef __attribute__((address_space(3))) void las_void;

__device__ __forceinline__ unsigned short f2bf(float f) {
  unsigned u = __float_as_uint(f);
  u += 0x7fffu + ((u >> 16) & 1u);
  return (unsigned short)(u >> 16);
}

__device__ __forceinline__ float fexp2(float x) {
#if __has_builtin(__builtin_amdgcn_exp2f)
  return __builtin_amdgcn_exp2f(x);
#else
  return __expf(x * 0.6931471805599453f);
#endif
}

// RNE pack via integer ops (prep/Q path)
__device__ __forceinline__ unsigned pack_bf2(float a, float b) {
  unsigned ua = __float_as_uint(a); ua += 0x7fffu + ((ua >> 16) & 1u);
  unsigned ub = __float_as_uint(b); ub += 0x7fffu + ((ub >> 16) & 1u);
  return __builtin_amdgcn_perm(ub, ua, 0x07060302u);
}

// HW packed f32->bf16x2: dst[15:0]=bf16(lo), dst[31:16]=bf16(hi). 1 VALU op.
__device__ __forceinline__ unsigned cvtpk(float lo, float hi) {
  unsigned r;
  asm("v_cvt_pk_bf16_f32 %0, %1, %2" : "=v"(r) : "v"(lo), "v"(hi));
  return r;
}

// bool-byte word (bytes in {0,1}) -> 4-bit nibble, bit j = byte j
__device__ __forceinline__ unsigned nib4(unsigned w) {
  return ((w * 0x01020408u) >> 24) & 0xFu;
}

// V-image column for physical key p (inverse of the B-frag handoff map):
// QK 32x32 C/D gives lane-half hl reg r the key (r&3)+8*(r>>2)+4*hl (+32*kt2).
// Choosing image col c = 16*kc + 8*hl + j to hold physical key
// 32*(kc>>1) + 16*(kc&1) + 8*(j>>2) + 4*hl + (j&3) makes PV's B slot j at
// key-group kc exactly C/D reg 8*(kc&1)+j of st[kc>>1] -- P stays lane-local.
__device__ __forceinline__ int vcol(int p) {
  const int kc = 2 * (p >> 5) + ((p >> 4) & 1);
  return 16 * kc + 8 * ((p >> 2) & 1) + 4 * ((p >> 3) & 1) + (p & 3);
}

// ---------------------------------------------------------------------------
// Fused prep kernel (2 launches total: prep + main).
//  blocks [0, CONVBLK): K -> bf16 images (IDENTITY row order), V -> bf16
//    transposed images with PERMUTED key columns (vcol). Element c of row r
//    at byte (c*2) ^ ((r&7)<<4) -- the main kernel's exact LDS image.
//  blocks [CONVBLK, ...): pack mask bits (physical key order), with
//    block-local byte-vs-word layout self-detection.
// ---------------------------------------------------------------------------
__global__ __launch_bounds__(256) void prep_kernel(
    const float* __restrict__ kk, const float* __restrict__ vv,
    const void* __restrict__ mask,
    char* __restrict__ kb, char* __restrict__ vb,
    unsigned* __restrict__ packed) {
  const int tid = threadIdx.x;
  if (blockIdx.x >= CONVBLK) {  // ---- mask pack with self-detect
    const int w = (blockIdx.x - CONVBLK) * 256 + tid;
    const uint4* bp = (const uint4*)((const char*)mask + (size_t)w * 32);
    uint4 x = bp[0], y = bp[1];
    const unsigned orw = (x.x | x.y) | (x.z | x.w) | (y.x | y.y) | (y.z | y.w);
    __shared__ int s0, sm;
    if (tid == 0) { s0 = 0; sm = 0; }
    __syncthreads();
    const int lane0 = ((tid & 63) == 0);
    if (__any((orw & 0x000000ffu) != 0) && lane0) atomicOr(&s0, 1);
    if (__any((orw & 0xffffff00u) != 0) && lane0) atomicOr(&sm, 1);
    __syncthreads();
    unsigned bits;
    if (s0 && sm) {  // byte bools
      bits = nib4(x.x) | (nib4(x.y) << 4) | (nib4(x.z) << 8) | (nib4(x.w) << 12) |
             (nib4(y.x) << 16) | (nib4(y.y) << 20) | (nib4(y.z) << 24) | (nib4(y.w) << 28);
    } else {  // 32-bit words
      const unsigned* m = (const unsigned*)mask + (size_t)w * 32;
      bits = 0u;
#pragma unroll
      for (int j = 0; j < 32; j++) bits |= (m[j] ? 1u : 0u) << j;
    }
    packed[w] = bits;
    return;
  }
  // ---- conv
  const int bid = blockIdx.x;  // bh*32 + t
  const int t = bid & 31;
  const int bh = bid >> 5;
  const int b = bh >> 4, h = bh & 15;
  char* kimg = kb + (size_t)bid * IMGB;
  char* vimg = vb + (size_t)bid * IMGB;

  {  // K: thread -> (key row r, 16-d group); identity rows, 8B swizzled writes
    const int r = tid >> 2;
    const int dg = (tid & 3) << 4;
    const float* src = kk + (((size_t)(b * SLEN + t * 64 + r) * NH + h) * DH + dg);
    char* rowp = kimg + r * 128;
    const int swzk = (r & 7) << 4;
#pragma unroll
    for (int i = 0; i < 4; i++) {
      float4v x = *(const float4v*)(src + i * 4);
      const int d0 = dg + i * 4;
      const int off = (d0 * 2) ^ swzk;
      union { unsigned u[2]; short4v s4; } cv;
      cv.u[0] = pack_bf2(x.x, x.y);
      cv.u[1] = pack_bf2(x.z, x.w);
      *(short4v*)(rowp + off) = cv.s4;
    }
  }
  {  // V transposed: row = d, col = vcol(physical key), 2B scatter
    const int d = tid >> 2;
    const int kg = (tid & 3) << 4;
    char* rowp = vimg + d * 128;
    const int swzv = (d & 7) << 4;
    const float* src = vv + ((size_t)(b * SLEN + t * 64 + kg) * NH + h) * DH + d;
#pragma unroll
    for (int i = 0; i < 16; i++) {
      const int p = kg + i;
      float x = src[(size_t)i * (NH * DH)];
      const int off = (vcol(p) * 2) ^ swzv;
      *(unsigned short*)(rowp + off) = f2bf(x);
    }
  }
}

// ---------------------------------------------------------------------------
// Main kernel: 32x32x16 MFMAs. 256 threads = 4 waves x 32 queries = 128 q per
// block; grid 512 = 2 blocks/CU. Per wave/round: 8 QK + 8 PV + 4 ones-l MFMAs,
// 16 ds_read_b128. 2x arithmetic intensity vs 16x16x32 (LDS/CU/round halves:
// 256->128 KB -- LDS read BW was the most-loaded pipe at ~60-70%).
// C/D: col=lane&31 (q; lane-local softmax), row=(r&3)+8*(r>>2)+4*hl.
// A/B k-map: kappa(hl,j)=8*hl+j (pattern verified at 16x16x32).
// P->PV handoff pure-register via the vcol V-image permutation.
// ---------------------------------------------------------------------------
__global__ __launch_bounds__(256, 2) void sattn_fast7(
    const float* __restrict__ q, const unsigned* __restrict__ pmask,
    const char* __restrict__ kb, const char* __restrict__ vb,
    float* __restrict__ out) {
  __shared__ __align__(16) char Kbuf[2][IMGB];
  __shared__ __align__(16) char Vbuf[2][IMGB];

  const int tid = threadIdx.x;
  const int xcd = blockIdx.x & 7;
  const int j = blockIdx.x >> 3;            // 0..63
  const int bh = xcd * 4 + (j >> 4);        // 4 bh per XCD -> images L2-resident
  const int chunk = j & 15;                 // 16 chunks of 128 queries
  const int b = bh >> 4;
  const int hd = bh & 15;
  const int wave = tid >> 6;
  const int lane = tid & 63;
  const int l31 = lane & 31;
  const int hl = lane >> 5;
  const int swz = (l31 & 7) << 4;

  const int qrow = chunk * 128 + wave * 32 + l31;
  const int qw = qrow * WPR;

  // Q B-frags, pre-scaled by (1/sqrt(64))*log2(e); qf[ds] elem j = Q[q][16ds+8hl+j]
  const float SCL2 = 0.18033688011112042f;
  short8v qf[4];
  {
    const float* qp = q + (((size_t)b * SLEN + qrow) * NH + hd) * DH;
#pragma unroll
    for (int ds = 0; ds < 4; ds++) {
      float4v x0 = *(const float4v*)(qp + ds * 16 + hl * 8);
      float4v x1 = *(const float4v*)(qp + ds * 16 + hl * 8 + 4);
      union { unsigned u[4]; short8v s8; } cv;
      cv.u[0] = pack_bf2(x0.x * SCL2, x0.y * SCL2);
      cv.u[1] = pack_bf2(x0.z * SCL2, x0.w * SCL2);
      cv.u[2] = pack_bf2(x1.x * SCL2, x1.y * SCL2);
      cv.u[3] = pack_bf2(x1.z * SCL2, x1.w * SCL2);
      qf[ds] = cv.s8;
    }
  }

  // all-ones A-frag (bf16 1.0) for the l-accumulating MFMA
  short8v ones;
#pragma unroll
  for (int i = 0; i < 8; i++) ones[i] = (short)0x3F80;

  // staging pointers: linear copy, 256 lanes x 16B x 2 shots per 8KB image
  const char* gK = kb + (size_t)bh * (NROUND * IMGB) + tid * 16;
  const char* gV = vb + (size_t)bh * (NROUND * IMGB) + tid * 16;

  float16v acc0 = {}, acc1 = {}, lacc = {};

  uint2 m = *(const uint2*)&pmask[qw];

  {  // prologue: stage round 0 into buffer 0
    char* lK = &Kbuf[0][0] + tid * 16;
    char* lV = &Vbuf[0][0] + tid * 16;
#pragma unroll
    for (int i = 0; i < 2; i++) {
      __builtin_amdgcn_global_load_lds((gas_void*)(gK + i * 4096), (las_void*)(lK + i * 4096), 16, 0, 0);
      __builtin_amdgcn_global_load_lds((gas_void*)(gV + i * 4096), (las_void*)(lV + i * 4096), 16, 0, 0);
    }
  }
  __syncthreads();

  for (int t = 0; t < NROUND; t++) {
    const int bt = t & 1;
    const unsigned m0 = m.x, m1 = m.y;
    if (t + 1 < NROUND) {
      m = *(const uint2*)&pmask[qw + 2 * (t + 1)];
      const char* nK = gK + (size_t)(t + 1) * IMGB;
      const char* nV = gV + (size_t)(t + 1) * IMGB;
      char* lK = &Kbuf[bt ^ 1][0] + tid * 16;
      char* lV = &Vbuf[bt ^ 1][0] + tid * 16;
#pragma unroll
      for (int i = 0; i < 2; i++) {
        __builtin_amdgcn_global_load_lds((gas_void*)(nK + i * 4096), (las_void*)(lK + i * 4096), 16, 0, 0);
        __builtin_amdgcn_global_load_lds((gas_void*)(nV + i * 4096), (las_void*)(lV + i * 4096), 16, 0, 0);
      }
    }

    // ---- phase 1: QK^T. st[kt2] reg r = score for key 32*kt2+(r&3)+8*(r>>2)+4*hl
    const char* Kl = &Kbuf[bt][0];
    float16v st0, st1;
    __builtin_amdgcn_s_setprio(1);
    {
      float16v z = {};
#pragma unroll
      for (int ds = 0; ds < 4; ds++) {
        short8v kf = *(const short8v*)(Kl + (l31)*128 + ((ds * 32 + hl * 16) ^ swz));
        z = __builtin_amdgcn_mfma_f32_32x32x16_bf16(kf, qf[ds], z, 0, 0, 0);
      }
      st0 = z;
    }
    {
      float16v z = {};
#pragma unroll
      for (int ds = 0; ds < 4; ds++) {
        short8v kf = *(const short8v*)(Kl + (32 + l31) * 128 + ((ds * 32 + hl * 16) ^ swz));
        z = __builtin_amdgcn_mfma_f32_32x32x16_bf16(kf, qf[ds], z, 0, 0, 0);
      }
      st1 = z;
    }
    __builtin_amdgcn_s_setprio(0);

    // ---- phase 2: softmax + mask + cvt_pk pack
    float p0[16], p1[16];
#pragma unroll
    for (int u = 0; u < 4; u++) {
      const unsigned hw0 = m0 >> (8 * u + 4 * hl);
      const unsigned hw1 = m1 >> (8 * u + 4 * hl);
      {
        float a0 = fexp2(st0[4 * u + 0]); a0 = (hw0 & 1u) ? a0 : 0.f;
        float a1 = fexp2(st0[4 * u + 1]); a1 = (hw0 & 2u) ? a1 : 0.f;
        float a2 = fexp2(st0[4 * u + 2]); a2 = (hw0 & 4u) ? a2 : 0.f;
        float a3 = fexp2(st0[4 * u + 3]); a3 = (hw0 & 8u) ? a3 : 0.f;
        p0[4 * u + 0] = a0; p0[4 * u + 1] = a1; p0[4 * u + 2] = a2; p0[4 * u + 3] = a3;
      }
      {
        float a0 = fexp2(st1[4 * u + 0]); a0 = (hw1 & 1u) ? a0 : 0.f;
        float a1 = fexp2(st1[4 * u + 1]); a1 = (hw1 & 2u) ? a1 : 0.f;
        float a2 = fexp2(st1[4 * u + 2]); a2 = (hw1 & 4u) ? a2 : 0.f;
        float a3 = fexp2(st1[4 * u + 3]); a3 = (hw1 & 8u) ? a3 : 0.f;
        p1[4 * u + 0] = a0; p1[4 * u + 1] = a1; p1[4 * u + 2] = a2; p1[4 * u + 3] = a3;
      }
    }
    // pf[kc] = B-frag of key-group kc: slot j = C/D reg 8*(kc&1)+j of st[kc>>1]
    short8v pf[4];
    {
      union { unsigned u[4]; short8v s8; } c0, c1, c2, c3;
#pragma unroll
      for (int jj = 0; jj < 4; jj++) {
        c0.u[jj] = cvtpk(p0[2 * jj], p0[2 * jj + 1]);
        c1.u[jj] = cvtpk(p0[8 + 2 * jj], p0[8 + 2 * jj + 1]);
        c2.u[jj] = cvtpk(p1[2 * jj], p1[2 * jj + 1]);
        c3.u[jj] = cvtpk(p1[8 + 2 * jj], p1[8 + 2 * jj + 1]);
      }
      pf[0] = c0.s8; pf[1] = c1.s8; pf[2] = c2.s8; pf[3] = c3.s8;
    }

    // ---- phase 3: PV (V image cols pre-permuted) + ones-l
    const char* Vl = &Vbuf[bt][0];
    __builtin_amdgcn_s_setprio(1);
#pragma unroll
    for (int kc = 0; kc < 4; kc++) {
      short8v vf0 = *(const short8v*)(Vl + (l31)*128 + ((kc * 32 + hl * 16) ^ swz));
      acc0 = __builtin_amdgcn_mfma_f32_32x32x16_bf16(vf0, pf[kc], acc0, 0, 0, 0);
      short8v vf1 = *(const short8v*)(Vl + (32 + l31) * 128 + ((kc * 32 + hl * 16) ^ swz));
      acc1 = __builtin_amdgcn_mfma_f32_32x32x16_bf16(vf1, pf[kc], acc1, 0, 0, 0);
      lacc = __builtin_amdgcn_mfma_f32_32x32x16_bf16(ones, pf[kc], lacc, 0, 0, 0);
    }
    __builtin_amdgcn_s_setprio(0);
    __syncthreads();
  }

  // lacc rows are identical: lacc[0] = sum over all 2048 keys of P[.][q]
  const float l = lacc[0];
  const float inv = (l > 0.f) ? 1.f / l : 0.f;
  float* op = out + (((size_t)b * SLEN + qrow) * NH + hd) * DH;
#pragma unroll
  for (int u = 0; u < 4; u++) {
    float4v o0, o1;
    o0.x = acc0[4 * u + 0] * inv; o0.y = acc0[4 * u + 1] * inv;
    o0.z = acc0[4 * u + 2] * inv; o0.w = acc0[4 * u + 3] * inv;
    o1.x = acc1[4 * u + 0] * inv; o1.y = acc1[4 * u + 1] * inv;
    o1.z = acc1[4 * u + 2] * inv; o1.w = acc1[4 * u + 3] * inv;
    *(float4v*)(op + 8 * u + 4 * hl) = o0;
    *(float4v*)(op + 32 + 8 * u + 4 * hl) = o1;
  }
}

// ---------------------------------------------------------------------------
// Fallback (R1 kernel, verified): used only if ws_size can't hold the images.
// ---------------------------------------------------------------------------
__global__ __launch_bounds__(256) void sattn_fallback(
    const float* __restrict__ q, const float* __restrict__ kk,
    const float* __restrict__ vv, const unsigned int* __restrict__ pmask,
    float* __restrict__ out) {
  __shared__ __align__(16) unsigned short Kt[16 * 64];
  __shared__ __align__(16) unsigned short Vt[64 * 20];

  const int tid = threadIdx.x;
  const int chunk = blockIdx.x & 31;
  const int bh = blockIdx.x >> 5;
  const int b = bh >> 4;
  const int h = bh & 15;
  const int wave = tid >> 6;
  const int lane = tid & 63;
  const int lq = lane & 15;
  const int g = lane >> 4;

  const int qrow = chunk * 64 + wave * 16 + lq;

  short4v qf[4];
  {
    const float* qp = q + (((size_t)b * SLEN + qrow) * NH + h) * DH;
#pragma unroll
    for (int ks = 0; ks < 4; ks++) {
      float4v x = *(const float4v*)(qp + ks * 16 + g * 4);
      short4v s;
      s.x = (short)f2bf(x.x); s.y = (short)f2bf(x.y);
      s.z = (short)f2bf(x.z); s.w = (short)f2bf(x.w);
      qf[ks] = s;
    }
  }

  const int srow = tid >> 4;
  const int scol = (tid & 15) * 4;
  const size_t kvbase = (size_t)b * SLEN * (NH * DH) + (size_t)h * DH;

  float4v acc[4] = {};
  float m_run = -INFINITY;
  float l_run = 0.f;

  for (int t = 0; t < SLEN / 16; t++) {
    const int kbase = t * 16;
    __syncthreads();
    {
      const size_t rowoff = kvbase + (size_t)(kbase + srow) * (NH * DH) + scol;
      float4v x = *(const float4v*)(kk + rowoff);
      short4v s;
      s.x = (short)f2bf(x.x); s.y = (short)f2bf(x.y);
      s.z = (short)f2bf(x.z); s.w = (short)f2bf(x.w);
      const int off = (scol * 2) ^ ((srow & 7) << 4);
      *(short4v*)((char*)Kt + srow * 128 + off) = s;

      float4v y = *(const float4v*)(vv + rowoff);
      Vt[(scol + 0) * 20 + srow] = f2bf(y.x);
      Vt[(scol + 1) * 20 + srow] = f2bf(y.y);
      Vt[(scol + 2) * 20 + srow] = f2bf(y.z);
      Vt[(scol + 3) * 20 + srow] = f2bf(y.w);
    }
    __syncthreads();

    float4v stv = {0.f, 0.f, 0.f, 0.f};
#pragma unroll
    for (int ks = 0; ks < 4; ks++) {
      const int off = ((ks * 16 + g * 4) * 2) ^ ((lq & 7) << 4);
      short4v kf = *(const short4v*)((const char*)Kt + lq * 128 + off);
      stv = __builtin_amdgcn_mfma_f32_16x16x16bf16_1k(kf, qf[ks], stv, 0, 0, 0);
    }

    const unsigned int mw = pmask[qrow * WPR + (kbase >> 5)];
    const int shift = (kbase & 16) + g * 4;
    float sc[4];
    float tmax = -INFINITY;
#pragma unroll
    for (int r = 0; r < 4; r++) {
      bool a = (mw >> (shift + r)) & 1u;
      sc[r] = a ? stv[r] * 0.125f : -INFINITY;
      tmax = fmaxf(tmax, sc[r]);
    }
    tmax = fmaxf(tmax, __shfl_xor(tmax, 16));
    tmax = fmaxf(tmax, __shfl_xor(tmax, 32));
    const float mnew = fmaxf(m_run, tmax);
    const float muse = (mnew > -1e37f) ? mnew : 0.f;
    const float alpha = __expf(m_run - muse);
    float p[4], tsum = 0.f;
#pragma unroll
    for (int r = 0; r < 4; r++) {
      p[r] = __expf(sc[r] - muse);
      tsum += p[r];
    }
    tsum += __shfl_xor(tsum, 16);
    tsum += __shfl_xor(tsum, 32);
    l_run = l_run * alpha + tsum;
    m_run = mnew;

    short4v pfv;
    pfv.x = (short)f2bf(p[0]); pfv.y = (short)f2bf(p[1]);
    pfv.z = (short)f2bf(p[2]); pfv.w = (short)f2bf(p[3]);

#pragma unroll
    for (int n = 0; n < 4; n++) {
      acc[n][0] *= alpha; acc[n][1] *= alpha;
      acc[n][2] *= alpha; acc[n][3] *= alpha;
      short4v vf = *(const short4v*)((const char*)Vt + ((n * 16 + lq) * 20 + g * 4) * 2);
      acc[n] = __builtin_amdgcn_mfma_f32_16x16x16bf16_1k(vf, pfv, acc[n], 0, 0, 0);
    }
  }

  const float inv = (l_run > 0.f) ? 1.f / l_run : 0.f;
  float* op = out + (((size_t)b * SLEN + qrow) * NH + h) * DH;
#pragma unroll
  for (int n = 0; n < 4; n++) {
    float4v o;
    o.x = acc[n][0] * inv; o.y = acc[n][1] * inv;
    o.z = acc[n][2] * inv; o.w = acc[n][3] * inv;
    *(float4v*)(op + n * 16 + g * 4) = o;
  }
}

extern "C" void kernel_launch(void* const* d_in, const int* in_sizes, int n_in,
                              void* d_out, int out_size, void* d_ws, size_t ws_size,
                              hipStream_t stream) {
  const float* q = (const float*)d_in[0];
  const float* k = (const float*)d_in[1];
  const float* v = (const float*)d_in[2];
  const void* mask = d_in[3];
  float* out = (float*)d_out;

  unsigned int* packed = (unsigned int*)((char*)d_ws + 256);
  char* kb = (char*)d_ws + (1 << 20);
  char* vb = kb + (size_t)NBATCH * NH * NROUND * IMGB;
  const size_t need = (size_t)(1 << 20) + 2 * (size_t)NBATCH * NH * NROUND * IMGB;

  prep_kernel<<<CONVBLK + PACKBLK, 256, 0, stream>>>(k, v, mask, kb, vb, packed);
  if (ws_size >= need) {
    sattn_fast7<<<NBATCH * NH * (SLEN / 128), 256, 0, stream>>>(q, packed, kb, vb, out);
  } else {
    sattn_fallback<<<NBATCH * NH * (SLEN / 64), 256, 0, stream>>>(q, k, v, packed, out);
  }
}

// Round 9
// 69.594 us; speedup vs baseline: 1.1573x; 1.1573x over previous
//
#include <hip/hip_runtime.h>
#include <hip/hip_bf16.h>
#include <math.h>

// SparseFlashAttention: B=2, S=2048, H=16, D=64, fp32 in/out, [S,S] bool mask.
#define SLEN 2048
#define NBATCH 2
#define NH 16
#define DH 64
#define WPR 64      // mask words per row
#define NROUND 32   // 64-key rounds
#define TILEB 16384 // bytes per 64-key fragment-image tile (K frags 0-7, V frags 8-15)
#define CONVBLK (NBATCH * NH * NROUND)          // 1024 conv blocks
#define PACKBLK (SLEN * WPR / 256)              // 512 pack blocks

typedef __attribute__((ext_vector_type(4))) short short4v;
typedef __attribute__((ext_vector_type(8))) short short8v;
typedef __attribute__((ext_vector_type(4))) float float4v;
typedef __attribute__((ext_vector_type(16))) float float16v;

__device__ __forceinline__ unsigned short f2bf(float f) {
  unsigned u = __float_as_uint(f);
  u += 0x7fffu + ((u >> 16) & 1u);
  return (unsigned short)(u >> 16);
}

__device__ __forceinline__ float fexp2(float x) {
#if __has_builtin(__builtin_amdgcn_exp2f)
  return __builtin_amdgcn_exp2f(x);
#else
  return __expf(x * 0.6931471805599453f);
#endif
}

// RNE pack via integer ops (prep/Q path)
__device__ __forceinline__ unsigned pack_bf2(float a, float b) {
  unsigned ua = __float_as_uint(a); ua += 0x7fffu + ((ua >> 16) & 1u);
  unsigned ub = __float_as_uint(b); ub += 0x7fffu + ((ub >> 16) & 1u);
  return __builtin_amdgcn_perm(ub, ua, 0x07060302u);
}

// HW packed f32->bf16x2: dst[15:0]=bf16(lo), dst[31:16]=bf16(hi). 1 VALU op.
__device__ __forceinline__ unsigned cvtpk(float lo, float hi) {
  unsigned r;
  asm("v_cvt_pk_bf16_f32 %0, %1, %2" : "=v"(r) : "v"(lo), "v"(hi));
  return r;
}

// bool-byte word (bytes in {0,1}) -> 4-bit nibble, bit j = byte j
__device__ __forceinline__ unsigned nib4(unsigned w) {
  return ((w * 0x01020408u) >> 24) & 0xFu;
}

// ---------------------------------------------------------------------------
// Fragment-image layout (R9): tile (bh, t) = 16 frags x 1024 B. Lane l of
// frag i reads bytes [i*1024 + l*16, +16) -- perfectly coalesced per wave.
//   K element (key r, dim d):  frag = (r>>5)*4 + (d>>4);
//     lane = ((d>>3)&1)*32 + (r&31); byte slot = (d&7)*2.
//   V element (key p, dim d):  frag = 8 + (d>>5)*4 + 2*(p>>5) + ((p>>4)&1);
//     lane = ((p>>2)&1)*32 + (d&31); slot = (4*((p>>3)&1) + (p&3))*2.
// These are exactly R8's HW-verified 32x32x16 A-frag / C->B handoff maps
// (kperm/vcol), re-expressed as (frag, lane) positions.
// ---------------------------------------------------------------------------
__global__ __launch_bounds__(256) void prep_kernel(
    const float* __restrict__ kk, const float* __restrict__ vv,
    const void* __restrict__ mask,
    char* __restrict__ img, unsigned* __restrict__ packed) {
  const int tid = threadIdx.x;
  if (blockIdx.x >= CONVBLK) {  // ---- mask pack with block-local self-detect
    const int w = (blockIdx.x - CONVBLK) * 256 + tid;
    const uint4* bp = (const uint4*)((const char*)mask + (size_t)w * 32);
    uint4 x = bp[0], y = bp[1];
    const unsigned orw = (x.x | x.y) | (x.z | x.w) | (y.x | y.y) | (y.z | y.w);
    __shared__ int s0, sm;
    if (tid == 0) { s0 = 0; sm = 0; }
    __syncthreads();
    const int lane0 = ((tid & 63) == 0);
    if (__any((orw & 0x000000ffu) != 0) && lane0) atomicOr(&s0, 1);
    if (__any((orw & 0xffffff00u) != 0) && lane0) atomicOr(&sm, 1);
    __syncthreads();
    unsigned bits;
    if (s0 && sm) {  // byte bools
      bits = nib4(x.x) | (nib4(x.y) << 4) | (nib4(x.z) << 8) | (nib4(x.w) << 12) |
             (nib4(y.x) << 16) | (nib4(y.y) << 20) | (nib4(y.z) << 24) | (nib4(y.w) << 28);
    } else {  // 32-bit words
      const unsigned* m = (const unsigned*)mask + (size_t)w * 32;
      bits = 0u;
#pragma unroll
      for (int j = 0; j < 32; j++) bits |= (m[j] ? 1u : 0u) << j;
    }
    packed[w] = bits;
    return;
  }
  // ---- conv
  const int bid = blockIdx.x;  // bh*32 + t
  const int t = bid & 31;
  const int bh = bid >> 5;
  const int b = bh >> 4, h = bh & 15;
  char* timg = img + (size_t)bid * TILEB;

  {  // K: thread -> (key r, 16-dim group dg); two 16B contiguous writes
    const int r = tid >> 2;
    const int dg = (tid & 3) << 4;
    const float* src = kk + (((size_t)(b * SLEN + t * 64 + r) * NH + h) * DH + dg);
    const int f = ((r >> 5) << 2) + (dg >> 4);
    char* base = timg + f * 1024 + (r & 31) * 16;  // hl=0 slot; hl=1 at +512
    float4v x0 = *(const float4v*)(src);
    float4v x1 = *(const float4v*)(src + 4);
    float4v x2 = *(const float4v*)(src + 8);
    float4v x3 = *(const float4v*)(src + 12);
    union { unsigned u[4]; short8v s8; } lo, hi;
    lo.u[0] = pack_bf2(x0.x, x0.y); lo.u[1] = pack_bf2(x0.z, x0.w);
    lo.u[2] = pack_bf2(x1.x, x1.y); lo.u[3] = pack_bf2(x1.z, x1.w);
    hi.u[0] = pack_bf2(x2.x, x2.y); hi.u[1] = pack_bf2(x2.z, x2.w);
    hi.u[2] = pack_bf2(x3.x, x3.y); hi.u[3] = pack_bf2(x3.z, x3.w);
    *(short8v*)(base) = lo.s8;
    *(short8v*)(base + 512) = hi.s8;
  }
  {  // V: thread -> (dim d, 16-key group kg); 2B transposed scatter
    const int d = tid >> 2;
    const int kg = (tid & 3) << 4;
    const float* src = vv + ((size_t)(b * SLEN + t * 64 + kg) * NH + h) * DH + d;
    const int fbase = 8 + ((d >> 5) << 2);
    const int l31d = d & 31;
#pragma unroll
    for (int i = 0; i < 16; i++) {
      const int p = kg + i;
      float x = src[(size_t)i * (NH * DH)];
      const int f = fbase + 2 * (p >> 5) + ((p >> 4) & 1);
      const int lane = ((p >> 2) & 1) * 32 + l31d;
      const int slot = 4 * ((p >> 3) & 1) + (p & 3);
      *(unsigned short*)(timg + f * 1024 + lane * 16 + slot * 2) = f2bf(x);
    }
  }
}

// ---------------------------------------------------------------------------
// Main kernel R9: NO LDS, NO BARRIERS. 256 threads = 4 independent waves,
// each owning 32 queries; fragments loaded straight from the L2-resident
// fragment-image via coalesced global dwordx4 (1024 B per instruction).
// Single-buffered rotate: K reloaded right after QK consumes it (use distance
// = softmax+PV), V right after PV (distance = QK+softmax) -- compiler-managed
// vmcnt gives software pipelining across rounds with no barrier drain.
// 32x32x16 MFMAs; P lane-local (verified maps); l summed on VALU, one shfl.
// ---------------------------------------------------------------------------
__global__ __launch_bounds__(256, 2) void sattn_fast8(
    const float* __restrict__ q, const unsigned* __restrict__ pmask,
    const char* __restrict__ img, float* __restrict__ out) {
  const int tid = threadIdx.x;
  const int xcd = blockIdx.x & 7;
  const int j = blockIdx.x >> 3;            // 0..63
  const int bh = xcd * 4 + (j >> 4);        // 4 bh per XCD -> images L2-resident
  const int chunk = j & 15;                 // 16 chunks of 128 queries
  const int b = bh >> 4;
  const int hd = bh & 15;
  const int wave = tid >> 6;
  const int lane = tid & 63;
  const int l31 = lane & 31;
  const int hl = lane >> 5;

  const int qrow = chunk * 128 + wave * 32 + l31;
  const int qw = qrow * WPR;

  // Q B-frags, pre-scaled by (1/sqrt(64))*log2(e); qf[ds] elem j = Q[q][16ds+8hl+j]
  const float SCL2 = 0.18033688011112042f;
  short8v qf[4];
  {
    const float* qp = q + (((size_t)b * SLEN + qrow) * NH + hd) * DH;
#pragma unroll
    for (int ds = 0; ds < 4; ds++) {
      float4v x0 = *(const float4v*)(qp + ds * 16 + hl * 8);
      float4v x1 = *(const float4v*)(qp + ds * 16 + hl * 8 + 4);
      union { unsigned u[4]; short8v s8; } cv;
      cv.u[0] = pack_bf2(x0.x * SCL2, x0.y * SCL2);
      cv.u[1] = pack_bf2(x0.z * SCL2, x0.w * SCL2);
      cv.u[2] = pack_bf2(x1.x * SCL2, x1.y * SCL2);
      cv.u[3] = pack_bf2(x1.z * SCL2, x1.w * SCL2);
      qf[ds] = cv.s8;
    }
  }

  // per-lane fragment pointer: frag i of round t at pt + t*TILEB + i*1024
  const char* pt = img + (size_t)bh * (NROUND * TILEB) + lane * 16;

  float16v acc0 = {}, acc1 = {};
  float lsum = 0.f;

  // prologue: round-0 fragments + mask
  short8v kf0 = *(const short8v*)(pt + 0 * 1024);
  short8v kf1 = *(const short8v*)(pt + 1 * 1024);
  short8v kf2 = *(const short8v*)(pt + 2 * 1024);
  short8v kf3 = *(const short8v*)(pt + 3 * 1024);
  short8v kf4 = *(const short8v*)(pt + 4 * 1024);
  short8v kf5 = *(const short8v*)(pt + 5 * 1024);
  short8v kf6 = *(const short8v*)(pt + 6 * 1024);
  short8v kf7 = *(const short8v*)(pt + 7 * 1024);
  short8v vf0 = *(const short8v*)(pt + 8 * 1024);
  short8v vf1 = *(const short8v*)(pt + 9 * 1024);
  short8v vf2 = *(const short8v*)(pt + 10 * 1024);
  short8v vf3 = *(const short8v*)(pt + 11 * 1024);
  short8v vf4 = *(const short8v*)(pt + 12 * 1024);
  short8v vf5 = *(const short8v*)(pt + 13 * 1024);
  short8v vf6 = *(const short8v*)(pt + 14 * 1024);
  short8v vf7 = *(const short8v*)(pt + 15 * 1024);
  uint2 m = *(const uint2*)&pmask[qw];

  for (int t = 0; t < NROUND; t++) {
    const unsigned m0 = m.x, m1 = m.y;
    const int tn = (t + 1 < NROUND) ? t + 1 : t;  // last-iter reload harmless
    const char* pn = pt + (size_t)tn * TILEB;

    // ---- QK^T: st0 = keys 0..31, st1 = keys 32..63 of this tile
    __builtin_amdgcn_s_setprio(1);
    float16v st0 = {}, st1 = {};
    st0 = __builtin_amdgcn_mfma_f32_32x32x16_bf16(kf0, qf[0], st0, 0, 0, 0);
    st1 = __builtin_amdgcn_mfma_f32_32x32x16_bf16(kf4, qf[0], st1, 0, 0, 0);
    st0 = __builtin_amdgcn_mfma_f32_32x32x16_bf16(kf1, qf[1], st0, 0, 0, 0);
    st1 = __builtin_amdgcn_mfma_f32_32x32x16_bf16(kf5, qf[1], st1, 0, 0, 0);
    st0 = __builtin_amdgcn_mfma_f32_32x32x16_bf16(kf2, qf[2], st0, 0, 0, 0);
    st1 = __builtin_amdgcn_mfma_f32_32x32x16_bf16(kf6, qf[2], st1, 0, 0, 0);
    st0 = __builtin_amdgcn_mfma_f32_32x32x16_bf16(kf3, qf[3], st0, 0, 0, 0);
    st1 = __builtin_amdgcn_mfma_f32_32x32x16_bf16(kf7, qf[3], st1, 0, 0, 0);
    __builtin_amdgcn_s_setprio(0);

    // ---- reload K for next round (use distance = softmax + PV)
    kf0 = *(const short8v*)(pn + 0 * 1024);
    kf1 = *(const short8v*)(pn + 1 * 1024);
    kf2 = *(const short8v*)(pn + 2 * 1024);
    kf3 = *(const short8v*)(pn + 3 * 1024);
    kf4 = *(const short8v*)(pn + 4 * 1024);
    kf5 = *(const short8v*)(pn + 5 * 1024);
    kf6 = *(const short8v*)(pn + 6 * 1024);
    kf7 = *(const short8v*)(pn + 7 * 1024);
    m = *(const uint2*)&pmask[qw + 2 * tn];

    // ---- softmax + mask + pack (reg r of st_h <-> key 32h+(r&3)+8*(r>>2)+4*hl)
    float p0[16], p1[16];
#pragma unroll
    for (int u = 0; u < 4; u++) {
      const unsigned hw0 = m0 >> (8 * u + 4 * hl);
      const unsigned hw1 = m1 >> (8 * u + 4 * hl);
      {
        float a0 = fexp2(st0[4 * u + 0]); a0 = (hw0 & 1u) ? a0 : 0.f;
        float a1 = fexp2(st0[4 * u + 1]); a1 = (hw0 & 2u) ? a1 : 0.f;
        float a2 = fexp2(st0[4 * u + 2]); a2 = (hw0 & 4u) ? a2 : 0.f;
        float a3 = fexp2(st0[4 * u + 3]); a3 = (hw0 & 8u) ? a3 : 0.f;
        lsum += (a0 + a1) + (a2 + a3);
        p0[4 * u + 0] = a0; p0[4 * u + 1] = a1; p0[4 * u + 2] = a2; p0[4 * u + 3] = a3;
      }
      {
        float a0 = fexp2(st1[4 * u + 0]); a0 = (hw1 & 1u) ? a0 : 0.f;
        float a1 = fexp2(st1[4 * u + 1]); a1 = (hw1 & 2u) ? a1 : 0.f;
        float a2 = fexp2(st1[4 * u + 2]); a2 = (hw1 & 4u) ? a2 : 0.f;
        float a3 = fexp2(st1[4 * u + 3]); a3 = (hw1 & 8u) ? a3 : 0.f;
        lsum += (a0 + a1) + (a2 + a3);
        p1[4 * u + 0] = a0; p1[4 * u + 1] = a1; p1[4 * u + 2] = a2; p1[4 * u + 3] = a3;
      }
    }
    // pf[kc] = B-frag of key-group kc: slot j = C/D reg 8*(kc&1)+j of st[kc>>1]
    short8v pf0, pf1, pf2, pf3;
    {
      union { unsigned u[4]; short8v s8; } c0, c1, c2, c3;
#pragma unroll
      for (int jj = 0; jj < 4; jj++) {
        c0.u[jj] = cvtpk(p0[2 * jj], p0[2 * jj + 1]);
        c1.u[jj] = cvtpk(p0[8 + 2 * jj], p0[8 + 2 * jj + 1]);
        c2.u[jj] = cvtpk(p1[2 * jj], p1[2 * jj + 1]);
        c3.u[jj] = cvtpk(p1[8 + 2 * jj], p1[8 + 2 * jj + 1]);
      }
      pf0 = c0.s8; pf1 = c1.s8; pf2 = c2.s8; pf3 = c3.s8;
    }

    // ---- PV (V-frag kc for d-half n: vf[n*4+kc])
    __builtin_amdgcn_s_setprio(1);
    acc0 = __builtin_amdgcn_mfma_f32_32x32x16_bf16(vf0, pf0, acc0, 0, 0, 0);
    acc1 = __builtin_amdgcn_mfma_f32_32x32x16_bf16(vf4, pf0, acc1, 0, 0, 0);
    acc0 = __builtin_amdgcn_mfma_f32_32x32x16_bf16(vf1, pf1, acc0, 0, 0, 0);
    acc1 = __builtin_amdgcn_mfma_f32_32x32x16_bf16(vf5, pf1, acc1, 0, 0, 0);
    acc0 = __builtin_amdgcn_mfma_f32_32x32x16_bf16(vf2, pf2, acc0, 0, 0, 0);
    acc1 = __builtin_amdgcn_mfma_f32_32x32x16_bf16(vf6, pf2, acc1, 0, 0, 0);
    acc0 = __builtin_amdgcn_mfma_f32_32x32x16_bf16(vf3, pf3, acc0, 0, 0, 0);
    acc1 = __builtin_amdgcn_mfma_f32_32x32x16_bf16(vf7, pf3, acc1, 0, 0, 0);
    __builtin_amdgcn_s_setprio(0);

    // ---- reload V for next round (use distance = next QK + softmax)
    vf0 = *(const short8v*)(pn + 8 * 1024);
    vf1 = *(const short8v*)(pn + 9 * 1024);
    vf2 = *(const short8v*)(pn + 10 * 1024);
    vf3 = *(const short8v*)(pn + 11 * 1024);
    vf4 = *(const short8v*)(pn + 12 * 1024);
    vf5 = *(const short8v*)(pn + 13 * 1024);
    vf6 = *(const short8v*)(pn + 14 * 1024);
    vf7 = *(const short8v*)(pn + 15 * 1024);
  }

  // q=l31 row total = this lane's partial + the other hl's partial
  lsum += __shfl_xor(lsum, 32);
  const float inv = (lsum > 0.f) ? 1.f / lsum : 0.f;
  float* op = out + (((size_t)b * SLEN + qrow) * NH + hd) * DH;
#pragma unroll
  for (int u = 0; u < 4; u++) {
    float4v o0, o1;
    o0.x = acc0[4 * u + 0] * inv; o0.y = acc0[4 * u + 1] * inv;
    o0.z = acc0[4 * u + 2] * inv; o0.w = acc0[4 * u + 3] * inv;
    o1.x = acc1[4 * u + 0] * inv; o1.y = acc1[4 * u + 1] * inv;
    o1.z = acc1[4 * u + 2] * inv; o1.w = acc1[4 * u + 3] * inv;
    *(float4v*)(op + 8 * u + 4 * hl) = o0;
    *(float4v*)(op + 32 + 8 * u + 4 * hl) = o1;
  }
}

// ---------------------------------------------------------------------------
// Fallback (R1 kernel, verified): used only if ws_size can't hold the images.
// ---------------------------------------------------------------------------
__global__ __launch_bounds__(256) void sattn_fallback(
    const float* __restrict__ q, const float* __restrict__ kk,
    const float* __restrict__ vv, const unsigned int* __restrict__ pmask,
    float* __restrict__ out) {
  __shared__ __align__(16) unsigned short Kt[16 * 64];
  __shared__ __align__(16) unsigned short Vt[64 * 20];

  const int tid = threadIdx.x;
  const int chunk = blockIdx.x & 31;
  const int bh = blockIdx.x >> 5;
  const int b = bh >> 4;
  const int h = bh & 15;
  const int wave = tid >> 6;
  const int lane = tid & 63;
  const int lq = lane & 15;
  const int g = lane >> 4;

  const int qrow = chunk * 64 + wave * 16 + lq;

  short4v qf[4];
  {
    const float* qp = q + (((size_t)b * SLEN + qrow) * NH + h) * DH;
#pragma unroll
    for (int ks = 0; ks < 4; ks++) {
      float4v x = *(const float4v*)(qp + ks * 16 + g * 4);
      short4v s;
      s.x = (short)f2bf(x.x); s.y = (short)f2bf(x.y);
      s.z = (short)f2bf(x.z); s.w = (short)f2bf(x.w);
      qf[ks] = s;
    }
  }

  const int srow = tid >> 4;
  const int scol = (tid & 15) * 4;
  const size_t kvbase = (size_t)b * SLEN * (NH * DH) + (size_t)h * DH;

  float4v acc[4] = {};
  float m_run = -INFINITY;
  float l_run = 0.f;

  for (int t = 0; t < SLEN / 16; t++) {
    const int kbase = t * 16;
    __syncthreads();
    {
      const size_t rowoff = kvbase + (size_t)(kbase + srow) * (NH * DH) + scol;
      float4v x = *(const float4v*)(kk + rowoff);
      short4v s;
      s.x = (short)f2bf(x.x); s.y = (short)f2bf(x.y);
      s.z = (short)f2bf(x.z); s.w = (short)f2bf(x.w);
      const int off = (scol * 2) ^ ((srow & 7) << 4);
      *(short4v*)((char*)Kt + srow * 128 + off) = s;

      float4v y = *(const float4v*)(vv + rowoff);
      Vt[(scol + 0) * 20 + srow] = f2bf(y.x);
      Vt[(scol + 1) * 20 + srow] = f2bf(y.y);
      Vt[(scol + 2) * 20 + srow] = f2bf(y.z);
      Vt[(scol + 3) * 20 + srow] = f2bf(y.w);
    }
    __syncthreads();

    float4v stv = {0.f, 0.f, 0.f, 0.f};
#pragma unroll
    for (int ks = 0; ks < 4; ks++) {
      const int off = ((ks * 16 + g * 4) * 2) ^ ((lq & 7) << 4);
      short4v kf = *(const short4v*)((const char*)Kt + lq * 128 + off);
      stv = __builtin_amdgcn_mfma_f32_16x16x16bf16_1k(kf, qf[ks], stv, 0, 0, 0);
    }

    const unsigned int mw = pmask[qrow * WPR + (kbase >> 5)];
    const int shift = (kbase & 16) + g * 4;
    float sc[4];
    float tmax = -INFINITY;
#pragma unroll
    for (int r = 0; r < 4; r++) {
      bool a = (mw >> (shift + r)) & 1u;
      sc[r] = a ? stv[r] * 0.125f : -INFINITY;
      tmax = fmaxf(tmax, sc[r]);
    }
    tmax = fmaxf(tmax, __shfl_xor(tmax, 16));
    tmax = fmaxf(tmax, __shfl_xor(tmax, 32));
    const float mnew = fmaxf(m_run, tmax);
    const float muse = (mnew > -1e37f) ? mnew : 0.f;
    const float alpha = __expf(m_run - muse);
    float p[4], tsum = 0.f;
#pragma unroll
    for (int r = 0; r < 4; r++) {
      p[r] = __expf(sc[r] - muse);
      tsum += p[r];
    }
    tsum += __shfl_xor(tsum, 16);
    tsum += __shfl_xor(tsum, 32);
    l_run = l_run * alpha + tsum;
    m_run = mnew;

    short4v pfv;
    pfv.x = (short)f2bf(p[0]); pfv.y = (short)f2bf(p[1]);
    pfv.z = (short)f2bf(p[2]); pfv.w = (short)f2bf(p[3]);

#pragma unroll
    for (int n = 0; n < 4; n++) {
      acc[n][0] *= alpha; acc[n][1] *= alpha;
      acc[n][2] *= alpha; acc[n][3] *= alpha;
      short4v vf = *(const short4v*)((const char*)Vt + ((n * 16 + lq) * 20 + g * 4) * 2);
      acc[n] = __builtin_amdgcn_mfma_f32_16x16x16bf16_1k(vf, pfv, acc[n], 0, 0, 0);
    }
  }

  const float inv = (l_run > 0.f) ? 1.f / l_run : 0.f;
  float* op = out + (((size_t)b * SLEN + qrow) * NH + h) * DH;
#pragma unroll
  for (int n = 0; n < 4; n++) {
    float4v o;
    o.x = acc[n][0] * inv; o.y = acc[n][1] * inv;
    o.z = acc[n][2] * inv; o.w = acc[n][3] * inv;
    *(float4v*)(op + n * 16 + g * 4) = o;
  }
}

extern "C" void kernel_launch(void* const* d_in, const int* in_sizes, int n_in,
                              void* d_out, int out_size, void* d_ws, size_t ws_size,
                              hipStream_t stream) {
  const float* q = (const float*)d_in[0];
  const float* k = (const float*)d_in[1];
  const float* v = (const float*)d_in[2];
  const void* mask = d_in[3];
  float* out = (float*)d_out;

  unsigned int* packed = (unsigned int*)((char*)d_ws + 256);
  char* img = (char*)d_ws + (1 << 20);
  const size_t need = (size_t)(1 << 20) + (size_t)CONVBLK * TILEB;

  prep_kernel<<<CONVBLK + PACKBLK, 256, 0, stream>>>(k, v, mask, img, packed);
  if (ws_size >= need) {
    sattn_fast8<<<NBATCH * NH * (SLEN / 128), 256, 0, stream>>>(q, packed, img, out);
  } else {
    sattn_fallback<<<NBATCH * NH * (SLEN / 64), 256, 0, stream>>>(q, k, v, packed, out);
  }
}